// Round 5
// baseline (109.194 us; speedup 1.0000x reference)
//
#include <hip/hip_runtime.h>

typedef _Float16 f16;
typedef __attribute__((ext_vector_type(4))) _Float16 f16x4;
typedef __attribute__((ext_vector_type(8))) _Float16 f16x8;
typedef __attribute__((ext_vector_type(4))) float f32x4;

#define CEXP 0.18033688011112042f  /* 0.125 * log2(e) : folded into Q at GEMM epilogue */
#define QKB_LD 1056   /* 1024 + 32: L2 channel spread */
#define VTB_LD 2080   /* 2048 + 32 */

__device__ __forceinline__ void gload16(const f16* g, f16* l) {
    __builtin_amdgcn_global_load_lds((const __attribute__((address_space(1))) void*)g,
                                     (__attribute__((address_space(3))) void*)l, 16, 0, 0);
}

// ---------------- fp32 -> f16 convert (vectorized) ----------------
__global__ __launch_bounds__(256) void conv_f32_f16_k(const float* __restrict__ in,
                                                      f16* __restrict__ out) {
    int idx = (blockIdx.x * 256 + threadIdx.x) * 8;
    float4 a = *(const float4*)(in + idx);
    float4 b = *(const float4*)(in + idx + 4);
    f16x8 o;
    o[0] = (f16)a.x; o[1] = (f16)a.y; o[2] = (f16)a.z; o[3] = (f16)a.w;
    o[4] = (f16)b.x; o[5] = (f16)b.y; o[6] = (f16)b.z; o[7] = (f16)b.w;
    *(f16x8*)(out + idx) = o;
}

// ---- transpose + convert: out[(row_off+n)*ldo + k] = in[k*N + n] ----
__global__ __launch_bounds__(256) void transpose_conv_k(const float* __restrict__ in,
                                                        f16* __restrict__ out,
                                                        int N, int ldo, int row_off) {
    __shared__ float tile[32][33];
    int tx = threadIdx.x & 31, ty = threadIdx.x >> 5;  // 32 x 8
    int n0 = blockIdx.x * 32, k0 = blockIdx.y * 32;
#pragma unroll
    for (int j = 0; j < 4; j++)
        tile[ty + j * 8][tx] = in[(size_t)(k0 + ty + j * 8) * N + n0 + tx];
    __syncthreads();
#pragma unroll
    for (int j = 0; j < 4; j++)
        out[(size_t)(row_off + n0 + ty + j * 8) * ldo + k0 + tx] = (f16)tile[tx][ty + j * 8];
}

// ---------------- 128x128 f16 MFMA GEMM (m97 structure) ----------------
// Staging via global_load_lds width=16, linear LDS [128][64] f16.
// MODE 0: f16 to Cqk (Q cols pre-scaled by CEXP), V transposed to Cvt.
// MODE 1: fp32 + bias to Cout.
template <int MODE>
__global__ __launch_bounds__(256) void gemm128_k(
    const f16* __restrict__ A, const f16* __restrict__ Bt,
    f16* __restrict__ Cqk, f16* __restrict__ Cvt,
    float* __restrict__ Cout, const float* __restrict__ bias,
    int K, int NTILES) {
    __shared__ __align__(16) f16 As[128 * 64];
    __shared__ __align__(16) f16 Bs[128 * 64];
    int bid = blockIdx.x;
    int nt = bid % NTILES, mt = bid / NTILES;
    int m0 = mt * 128, n0 = nt * 128;
    int tid = threadIdx.x;
    int lane = tid & 63, w = tid >> 6;
    int wm = w >> 1, wn = w & 1;
    int lr = lane & 15, lg = lane >> 4;
    int rowL = lane >> 3;          // 0..7
    int colL = (lane & 7) * 8;     // 16B chunk within 64-f16 row
    const f16* aSrc = A + (size_t)(m0 + w * 32 + rowL) * K + colL;
    const f16* bSrc = Bt + (size_t)(n0 + w * 32 + rowL) * K + colL;
    f32x4 acc[4][4] = {};

    for (int k0 = 0; k0 < K; k0 += 64) {
#pragma unroll
        for (int j = 0; j < 4; j++) {
            gload16(aSrc + k0 + (size_t)(j * 8) * K, &As[(w * 32 + j * 8) * 64]);
            gload16(bSrc + k0 + (size_t)(j * 8) * K, &Bs[(w * 32 + j * 8) * 64]);
        }
        __syncthreads();
#pragma unroll
        for (int ks = 0; ks < 2; ks++) {
            f16x8 af[4], bf[4];
#pragma unroll
            for (int i = 0; i < 4; i++)
                af[i] = *(const f16x8*)(&As[(wm * 64 + i * 16 + lr) * 64 + ks * 32 + lg * 8]);
#pragma unroll
            for (int j = 0; j < 4; j++)
                bf[j] = *(const f16x8*)(&Bs[(wn * 64 + j * 16 + lr) * 64 + ks * 32 + lg * 8]);
#pragma unroll
            for (int i = 0; i < 4; i++)
#pragma unroll
                for (int j = 0; j < 4; j++)
                    acc[i][j] = __builtin_amdgcn_mfma_f32_16x16x32_f16(af[i], bf[j], acc[i][j], 0, 0, 0);
        }
        __syncthreads();
    }

#pragma unroll
    for (int i = 0; i < 4; i++) {
#pragma unroll
        for (int j = 0; j < 4; j++) {
            int row = m0 + wm * 64 + i * 16 + lg * 4;
            int col = n0 + wn * 64 + j * 16 + lr;
            if (MODE == 1) {
                float bv = bias[col];
#pragma unroll
                for (int r = 0; r < 4; r++)
                    Cout[(size_t)(row + r) * 1024 + col] = acc[i][j][r] + bv;
            } else {
                if (col < 1024) {
                    float sc = (col < 512) ? CEXP : 1.0f;  // pre-scale Q for exp2-domain softmax
#pragma unroll
                    for (int r = 0; r < 4; r++)
                        Cqk[(size_t)(row + r) * QKB_LD + col] = (f16)(acc[i][j][r] * sc);
                } else {
                    int c = col - 1024;
                    int hh = c >> 6, d = c & 63;
                    int bb = row >> 11, n = row & 2047;
                    f16x4 ov;
#pragma unroll
                    for (int r = 0; r < 4; r++) ov[r] = (f16)acc[i][j][r];
                    *(f16x4*)(Cvt + (size_t)((bb * 8 + hh) * 64 + d) * VTB_LD + n) = ov;
                }
            }
        }
    }
}

// ---------------- flash attention: KVBLK=64, 32 KB LDS, 4 blocks/CU ----------------
// Block = 4 waves, QBLK=64 (16 q-rows/wave), KVBLK=64 staged via global_load_lds
// (zero staging VGPRs), double-buffered, one barrier/iter. Both-sides XOR swizzle
// (chunk granularity 16B): physChunk = chunk ^ (row&7); inverse-swizzled global
// source + swizzled ds_read. S^T = K*Q^T (D layout == PV B-operand layout).
// Q pre-scaled by 0.125*log2e -> exp2 direct. T13 defer-max (THR=8, log2 domain).
__global__ __launch_bounds__(256, 4) void attn_k(const f16* __restrict__ qkb,
                                                 const f16* __restrict__ vt,
                                                 f16* __restrict__ ao) {
    __shared__ __align__(16) f16 Ks[2][64 * 64];   // 8 KB each
    __shared__ __align__(16) f16 Vs[2][64 * 64];   // 8 KB each

    int bid = blockIdx.x;
    int xcd = bid & 7;
    int pair = xcd * 2 + ((bid >> 3) & 1);  // pin each pair's K/V to one XCD L2
    int qblk = bid >> 4;                    // 0..31
    int b = pair >> 3, h = pair & 7;
    int tid = threadIdx.x;
    int lane = tid & 63, w = tid >> 6;
    int lr = lane & 15, lg = lane >> 4;
    int q0 = qblk * 64 + w * 16;

    const f16* qb = qkb + (size_t)b * 2048 * QKB_LD + h * 64;
    const f16* kb = qb + 512;
    const f16* vb = vt + (size_t)pair * 64 * VTB_LD;

    // Q fragments (registers for whole kernel; already CEXP-scaled)
    f16x8 qf0 = *(const f16x8*)(qb + (size_t)(q0 + lr) * QKB_LD + lg * 8);
    f16x8 qf1 = *(const f16x8*)(qb + (size_t)(q0 + lr) * QKB_LD + 32 + lg * 8);

    // staging: call j covers 8 rows x 64 f16; lane -> row +(l>>3), phys chunk l&7,
    // so source logical chunk = (l&7) ^ (l>>3)  (inverse swizzle)
    int srcCol = (((lane & 7) ^ (lane >> 3)) << 3);
    int rowL = lane >> 3;
    const f16* ksrc = kb + (size_t)(w * 16 + rowL) * QKB_LD + srcCol;
    const f16* vsrc = vb + (size_t)(w * 16 + rowL) * VTB_LD + srcCol;

#pragma unroll
    for (int j = 0; j < 2; j++) {
        gload16(ksrc + (size_t)(j * 8) * QKB_LD, &Ks[0][(w * 16 + j * 8) * 64]);
        gload16(vsrc + (size_t)(j * 8) * VTB_LD, &Vs[0][(w * 16 + j * 8) * 64]);
    }
    __syncthreads();

    int kOffA = (lg * 8) ^ ((lr & 7) << 3);  // K read: swizzled element offset
    int lr7 = lr & 7;

    f32x4 acc[4] = {};
    float m = -INFINITY, l = 0.f;

    for (int t = 0; t < 32; t++) {
        int cur = t & 1;
        // ---- issue next tile's loads (drain at end-of-iter barrier) ----
        if (t < 31) {
            int kv1 = (t + 1) * 64;
            int nxt = cur ^ 1;
#pragma unroll
            for (int j = 0; j < 2; j++) {
                gload16(ksrc + (size_t)(kv1 + j * 8) * QKB_LD, &Ks[nxt][(w * 16 + j * 8) * 64]);
                gload16(vsrc + (size_t)(j * 8) * VTB_LD + kv1, &Vs[nxt][(w * 16 + j * 8) * 64]);
            }
        }

        // ---- QK^T: S^T tile [64 kv][16 q] per wave (already log2-scaled) ----
        f32x4 s[4];
        __builtin_amdgcn_s_setprio(1);
#pragma unroll
        for (int kg = 0; kg < 4; kg++) {
            const f16* krow = &Ks[cur][(kg * 16 + lr) * 64];
            f16x8 ka0 = *(const f16x8*)(krow + kOffA);
            f16x8 ka1 = *(const f16x8*)(krow + (kOffA ^ 32));
            f32x4 z = {};
            z = __builtin_amdgcn_mfma_f32_16x16x32_f16(ka0, qf0, z, 0, 0, 0);
            s[kg] = __builtin_amdgcn_mfma_f32_16x16x32_f16(ka1, qf1, z, 0, 0, 0);
        }
        __builtin_amdgcn_s_setprio(0);

        // ---- online softmax (exp2 domain), defer-max THR=8 ----
        float mx = -INFINITY;
#pragma unroll
        for (int kg = 0; kg < 4; kg++)
#pragma unroll
            for (int r = 0; r < 4; r++)
                mx = fmaxf(mx, s[kg][r]);
        mx = fmaxf(mx, __shfl_xor(mx, 16, 64));
        mx = fmaxf(mx, __shfl_xor(mx, 32, 64));
        if (!__all(mx - m <= 8.f)) {
            float mn = fmaxf(m, mx);
            float alpha = __builtin_amdgcn_exp2f(m - mn);
            m = mn;
            l *= alpha;
#pragma unroll
            for (int dg = 0; dg < 4; dg++)
#pragma unroll
                for (int r = 0; r < 4; r++)
                    acc[dg][r] *= alpha;
        }
        float rs = 0.f;
        f16x4 pf[4];
#pragma unroll
        for (int kg = 0; kg < 4; kg++)
#pragma unroll
            for (int r = 0; r < 4; r++) {
                float p = __builtin_amdgcn_exp2f(s[kg][r] - m);
                rs += p;
                pf[kg][r] = (f16)p;
            }
        rs += __shfl_xor(rs, 16, 64);
        rs += __shfl_xor(rs, 32, 64);
        l += rs;

        // ---- PV ----
        __builtin_amdgcn_s_setprio(1);
#pragma unroll
        for (int kg = 0; kg < 4; kg++)
#pragma unroll
            for (int dg = 0; dg < 4; dg++) {
                // logical col = kg*16 + lg*4 -> chunk kg*2+(lg>>1), sub-off (lg&1)*4
                int vpe = (((kg * 2 + (lg >> 1)) ^ lr7) << 3) + (lg & 1) * 4;
                f16x4 vf = *(const f16x4*)(&Vs[cur][(dg * 16 + lr) * 64 + vpe]);
                acc[dg] = __builtin_amdgcn_mfma_f32_16x16x16f16(vf, pf[kg], acc[dg], 0, 0, 0);
            }
        __builtin_amdgcn_s_setprio(0);

        __syncthreads();  // drains vmcnt(0): next buffer complete, cur reusable
    }

    float inv = 1.f / l;
#pragma unroll
    for (int dg = 0; dg < 4; dg++) {
        f16x4 ov;
#pragma unroll
        for (int r = 0; r < 4; r++) ov[r] = (f16)(acc[dg][r] * inv);
        *(f16x4*)(ao + (size_t)(b * 2048 + q0 + lr) * 512 + h * 64 + dg * 16 + lg * 4) = ov;
    }
}

extern "C" void kernel_launch(void* const* d_in, const int* in_sizes, int n_in,
                              void* d_out, int out_size, void* d_ws, size_t ws_size,
                              hipStream_t stream) {
    const float* x   = (const float*)d_in[0];
    const float* Wq  = (const float*)d_in[1];
    const float* Wkv = (const float*)d_in[2];
    const float* Wo  = (const float*)d_in[3];
    const float* bo  = (const float*)d_in[4];
    float* out = (float*)d_out;

    f16* xb    = (f16*)d_ws;                  // [4096][1024]
    f16* wqkvT = xb + 4096 * 1024;            // [1536][1024]
    f16* woT   = wqkvT + 1536 * 1024;         // [1024][512]
    f16* qkb   = woT + 1024 * 512;            // [4096][QKB_LD]  (Q*CEXP | K)
    f16* vtb   = qkb + 4096 * QKB_LD;         // [16][64][VTB_LD] V^T (padded)
    f16* ao    = vtb + 16 * 64 * VTB_LD;      // [4096][512]

    conv_f32_f16_k<<<2048, 256, 0, stream>>>(x, xb);
    transpose_conv_k<<<dim3(16, 32), 256, 0, stream>>>(Wq, wqkvT, 512, 1024, 0);
    transpose_conv_k<<<dim3(32, 32), 256, 0, stream>>>(Wkv, wqkvT, 1024, 1024, 512);
    transpose_conv_k<<<dim3(32, 16), 256, 0, stream>>>(Wo, woT, 1024, 512, 0);

    gemm128_k<0><<<32 * 12, 256, 0, stream>>>(xb, wqkvT, qkb, vtb, nullptr, nullptr, 1024, 12);
    attn_k<<<512, 256, 0, stream>>>(qkb, vtb, ao);
    gemm128_k<1><<<32 * 8, 256, 0, stream>>>(ao, woT, nullptr, nullptr, out, bo, 512, 8);
}

// Round 6
// 105.542 us; speedup vs baseline: 1.0346x; 1.0346x over previous
//
#include <hip/hip_runtime.h>

typedef _Float16 f16;
typedef __attribute__((ext_vector_type(4))) _Float16 f16x4;
typedef __attribute__((ext_vector_type(8))) _Float16 f16x8;
typedef __attribute__((ext_vector_type(4))) float f32x4;

#define CEXP 0.18033688011112042f  /* 0.125 * log2(e) : folded into Q at GEMM epilogue */
#define QKB_LD 1056   /* 1024 + 32: L2 channel spread */
#define VTB_LD 2080   /* 2048 + 32 */

__device__ __forceinline__ void gload16(const f16* g, f16* l) {
    __builtin_amdgcn_global_load_lds((const __attribute__((address_space(1))) void*)g,
                                     (__attribute__((address_space(3))) void*)l, 16, 0, 0);
}

// ---------------- fp32 -> f16 convert (vectorized) ----------------
__global__ __launch_bounds__(256) void conv_f32_f16_k(const float* __restrict__ in,
                                                      f16* __restrict__ out) {
    int idx = (blockIdx.x * 256 + threadIdx.x) * 8;
    float4 a = *(const float4*)(in + idx);
    float4 b = *(const float4*)(in + idx + 4);
    f16x8 o;
    o[0] = (f16)a.x; o[1] = (f16)a.y; o[2] = (f16)a.z; o[3] = (f16)a.w;
    o[4] = (f16)b.x; o[5] = (f16)b.y; o[6] = (f16)b.z; o[7] = (f16)b.w;
    *(f16x8*)(out + idx) = o;
}

// ---- transpose + convert: out[(row_off+n)*ldo + k] = in[k*N + n] ----
__global__ __launch_bounds__(256) void transpose_conv_k(const float* __restrict__ in,
                                                        f16* __restrict__ out,
                                                        int N, int ldo, int row_off) {
    __shared__ float tile[32][33];
    int tx = threadIdx.x & 31, ty = threadIdx.x >> 5;  // 32 x 8
    int n0 = blockIdx.x * 32, k0 = blockIdx.y * 32;
#pragma unroll
    for (int j = 0; j < 4; j++)
        tile[ty + j * 8][tx] = in[(size_t)(k0 + ty + j * 8) * N + n0 + tx];
    __syncthreads();
#pragma unroll
    for (int j = 0; j < 4; j++)
        out[(size_t)(row_off + n0 + ty + j * 8) * ldo + k0 + tx] = (f16)tile[tx][ty + j * 8];
}

// ---------------- 128xBN f16 MFMA GEMM (m97 structure) ----------------
// BN=64: 768 blocks for QKV (even 3/CU, kills the 1.5/CU tail).
// MODE 0: f16 to Cqk (Q cols pre-scaled by CEXP), V transposed to Cvt.
// MODE 1: fp32 + bias to Cout.
template <int MODE, int BN>
__global__ __launch_bounds__(256) void gemm_k(
    const f16* __restrict__ A, const f16* __restrict__ Bt,
    f16* __restrict__ Cqk, f16* __restrict__ Cvt,
    float* __restrict__ Cout, const float* __restrict__ bias,
    int K, int NTILES) {
    __shared__ __align__(16) f16 As[128 * 64];
    __shared__ __align__(16) f16 Bs[BN * 64];
    constexpr int MI = (BN == 128) ? 4 : 2;   // 16-row fragments per wave
    int bid = blockIdx.x;
    int nt = bid % NTILES, mt = bid / NTILES;
    int m0 = mt * 128, n0 = nt * BN;
    int tid = threadIdx.x;
    int lane = tid & 63, w = tid >> 6;
    int rowBase = (BN == 128) ? (w >> 1) * 64 : w * 32;
    int colBase = (BN == 128) ? (w & 1) * 64 : 0;
    int lr = lane & 15, lg = lane >> 4;
    int rowL = lane >> 3;          // 0..7
    int colL = (lane & 7) * 8;     // 16B chunk within 64-f16 row
    int bRow0 = (BN == 128) ? w * 32 : w * 16;
    const f16* aSrc = A + (size_t)(m0 + w * 32 + rowL) * K + colL;
    const f16* bSrc = Bt + (size_t)(n0 + bRow0 + rowL) * K + colL;
    f32x4 acc[MI][4] = {};

    for (int k0 = 0; k0 < K; k0 += 64) {
#pragma unroll
        for (int j = 0; j < 4; j++)
            gload16(aSrc + k0 + (size_t)(j * 8) * K, &As[(w * 32 + j * 8) * 64]);
#pragma unroll
        for (int j = 0; j < (BN == 128 ? 4 : 2); j++)
            gload16(bSrc + k0 + (size_t)(j * 8) * K, &Bs[(bRow0 + j * 8) * 64]);
        __syncthreads();
#pragma unroll
        for (int ks = 0; ks < 2; ks++) {
            f16x8 af[MI], bf[4];
#pragma unroll
            for (int i = 0; i < MI; i++)
                af[i] = *(const f16x8*)(&As[(rowBase + i * 16 + lr) * 64 + ks * 32 + lg * 8]);
#pragma unroll
            for (int j = 0; j < 4; j++)
                bf[j] = *(const f16x8*)(&Bs[(colBase + j * 16 + lr) * 64 + ks * 32 + lg * 8]);
#pragma unroll
            for (int i = 0; i < MI; i++)
#pragma unroll
                for (int j = 0; j < 4; j++)
                    acc[i][j] = __builtin_amdgcn_mfma_f32_16x16x32_f16(af[i], bf[j], acc[i][j], 0, 0, 0);
        }
        __syncthreads();
    }

#pragma unroll
    for (int i = 0; i < MI; i++) {
#pragma unroll
        for (int j = 0; j < 4; j++) {
            int row = m0 + rowBase + i * 16 + lg * 4;
            int col = n0 + colBase + j * 16 + lr;
            if (MODE == 1) {
                float bv = bias[col];
#pragma unroll
                for (int r = 0; r < 4; r++)
                    Cout[(size_t)(row + r) * 1024 + col] = acc[i][j][r] + bv;
            } else {
                if (col < 1024) {
                    float sc = (col < 512) ? CEXP : 1.0f;  // pre-scale Q for exp2-domain softmax
#pragma unroll
                    for (int r = 0; r < 4; r++)
                        Cqk[(size_t)(row + r) * QKB_LD + col] = (f16)(acc[i][j][r] * sc);
                } else {
                    int c = col - 1024;
                    int hh = c >> 6, d = c & 63;
                    int bb = row >> 11, n = row & 2047;
                    f16x4 ov;
#pragma unroll
                    for (int r = 0; r < 4; r++) ov[r] = (f16)acc[i][j][r];
                    *(f16x4*)(Cvt + (size_t)((bb * 8 + hh) * 64 + d) * VTB_LD + n) = ov;
                }
            }
        }
    }
}

// ---------------- flash attention: triple-buffered, counted vmcnt, no drain ----------------
// Block = 4 waves, QBLK=64 (16 q-rows/wave), KVBLK=64, 3 LDS buffers (48 KB).
// Iter t: issue gloads for tile t+2, compute tile t, s_waitcnt vmcnt(4)
// (ensures tile t+1 landed, keeps t+2 in flight), raw s_barrier (NO drain).
// Both-sides XOR swizzle at 16B-chunk granularity. S^T = K*Q^T (D layout ==
// PV B-operand layout -> zero shuffles). Q pre-scaled -> exp2 direct. T13 defer-max.
__global__ __launch_bounds__(256, 2) void attn_k(const f16* __restrict__ qkb,
                                                 const f16* __restrict__ vt,
                                                 f16* __restrict__ ao) {
    __shared__ __align__(16) f16 Ks[3][64 * 64];   // 8 KB each
    __shared__ __align__(16) f16 Vs[3][64 * 64];   // 8 KB each

    int bid = blockIdx.x;
    int xcd = bid & 7;
    int pair = xcd * 2 + ((bid >> 3) & 1);  // pin each pair's K/V to one XCD L2
    int qblk = bid >> 4;                    // 0..31
    int b = pair >> 3, h = pair & 7;
    int tid = threadIdx.x;
    int lane = tid & 63, w = tid >> 6;
    int lr = lane & 15, lg = lane >> 4;
    int q0 = qblk * 64 + w * 16;

    const f16* qb = qkb + (size_t)b * 2048 * QKB_LD + h * 64;
    const f16* kb = qb + 512;
    const f16* vb = vt + (size_t)pair * 64 * VTB_LD;

    // Q fragments (registers for whole kernel; already CEXP-scaled).
    // Drain them immediately so loop vmcnt counting sees only staging loads.
    f16x8 qf0 = *(const f16x8*)(qb + (size_t)(q0 + lr) * QKB_LD + lg * 8);
    f16x8 qf1 = *(const f16x8*)(qb + (size_t)(q0 + lr) * QKB_LD + 32 + lg * 8);
    asm volatile("s_waitcnt vmcnt(0)" ::: "memory");

    // staging: call j covers 8 rows x 64 f16; lane -> row +(l>>3), phys chunk l&7,
    // source logical chunk = (l&7) ^ (l>>3)  (inverse swizzle)
    int srcCol = (((lane & 7) ^ (lane >> 3)) << 3);
    int rowL = lane >> 3;
    const f16* ksrc = kb + (size_t)(w * 16 + rowL) * QKB_LD + srcCol;
    const f16* vsrc = vb + (size_t)(w * 16 + rowL) * VTB_LD + srcCol;

    auto stage = [&](int buf, int kv0) {
#pragma unroll
        for (int j = 0; j < 2; j++) {
            gload16(ksrc + (size_t)(kv0 + j * 8) * QKB_LD, &Ks[buf][(w * 16 + j * 8) * 64]);
            gload16(vsrc + (size_t)(j * 8) * VTB_LD + kv0, &Vs[buf][(w * 16 + j * 8) * 64]);
        }
    };

    stage(0, 0);
    stage(1, 64);
    asm volatile("s_waitcnt vmcnt(4)" ::: "memory");  // tile 0 landed; tile 1 in flight
    __builtin_amdgcn_s_barrier();
    asm volatile("" ::: "memory");

    int kOffA = (lg * 8) ^ ((lr & 7) << 3);  // K read: swizzled element offset
    int lr7 = lr & 7;

    f32x4 acc[4] = {};
    float m = -INFINITY, l = 0.f;
    int c0 = 0, c1 = 1, c2 = 2;  // c0 = current, c1 = next (landed), c2 = stage target

    for (int t = 0; t < 32; t++) {
        if (t < 30) stage(c2, (t + 2) * 64);  // issue early: ~2 iters to land

        // ---- QK^T: S^T tile [64 kv][16 q] per wave (already log2-scaled) ----
        f32x4 s[4];
        __builtin_amdgcn_s_setprio(1);
#pragma unroll
        for (int kg = 0; kg < 4; kg++) {
            const f16* krow = &Ks[c0][(kg * 16 + lr) * 64];
            f16x8 ka0 = *(const f16x8*)(krow + kOffA);
            f16x8 ka1 = *(const f16x8*)(krow + (kOffA ^ 32));
            f32x4 z = {};
            z = __builtin_amdgcn_mfma_f32_16x16x32_f16(ka0, qf0, z, 0, 0, 0);
            s[kg] = __builtin_amdgcn_mfma_f32_16x16x32_f16(ka1, qf1, z, 0, 0, 0);
        }
        __builtin_amdgcn_s_setprio(0);

        // ---- online softmax (exp2 domain), defer-max THR=8, tree reductions ----
        float t0 = fmaxf(fmaxf(s[0][0], s[0][1]), fmaxf(s[0][2], s[0][3]));
        float t1 = fmaxf(fmaxf(s[1][0], s[1][1]), fmaxf(s[1][2], s[1][3]));
        float t2 = fmaxf(fmaxf(s[2][0], s[2][1]), fmaxf(s[2][2], s[2][3]));
        float t3 = fmaxf(fmaxf(s[3][0], s[3][1]), fmaxf(s[3][2], s[3][3]));
        float mx = fmaxf(fmaxf(t0, t1), fmaxf(t2, t3));
        mx = fmaxf(mx, __shfl_xor(mx, 16, 64));
        mx = fmaxf(mx, __shfl_xor(mx, 32, 64));
        if (!__all(mx - m <= 8.f)) {
            float mn = fmaxf(m, mx);
            float alpha = __builtin_amdgcn_exp2f(m - mn);
            m = mn;
            l *= alpha;
#pragma unroll
            for (int dg = 0; dg < 4; dg++)
#pragma unroll
                for (int r = 0; r < 4; r++)
                    acc[dg][r] *= alpha;
        }
        f16x4 pf[4];
        float ps[4];
#pragma unroll
        for (int kg = 0; kg < 4; kg++) {
            float p0 = __builtin_amdgcn_exp2f(s[kg][0] - m);
            float p1 = __builtin_amdgcn_exp2f(s[kg][1] - m);
            float p2 = __builtin_amdgcn_exp2f(s[kg][2] - m);
            float p3 = __builtin_amdgcn_exp2f(s[kg][3] - m);
            pf[kg][0] = (f16)p0; pf[kg][1] = (f16)p1;
            pf[kg][2] = (f16)p2; pf[kg][3] = (f16)p3;
            ps[kg] = (p0 + p1) + (p2 + p3);
        }
        float rs = (ps[0] + ps[1]) + (ps[2] + ps[3]);
        rs += __shfl_xor(rs, 16, 64);
        rs += __shfl_xor(rs, 32, 64);
        l += rs;

        // ---- PV ----
        __builtin_amdgcn_s_setprio(1);
#pragma unroll
        for (int kg = 0; kg < 4; kg++)
#pragma unroll
            for (int dg = 0; dg < 4; dg++) {
                int vpe = (((kg * 2 + (lg >> 1)) ^ lr7) << 3) + (lg & 1) * 4;
                f16x4 vf = *(const f16x4*)(&Vs[c0][(dg * 16 + lr) * 64 + vpe]);
                acc[dg] = __builtin_amdgcn_mfma_f32_16x16x16f16(vf, pf[kg], acc[dg], 0, 0, 0);
            }
        __builtin_amdgcn_s_setprio(0);

        // ---- counted wait: tile t+1 landed, tile t+2 stays in flight ----
        if (t < 30) {
            asm volatile("s_waitcnt vmcnt(4)" ::: "memory");
        } else if (t == 30) {
            asm volatile("s_waitcnt vmcnt(0)" ::: "memory");
        }
        if (t < 31) {
            __builtin_amdgcn_s_barrier();
            asm volatile("" ::: "memory");
        }
        int tmp = c0; c0 = c1; c1 = c2; c2 = tmp;
    }

    float inv = 1.f / l;
#pragma unroll
    for (int dg = 0; dg < 4; dg++) {
        f16x4 ov;
#pragma unroll
        for (int r = 0; r < 4; r++) ov[r] = (f16)(acc[dg][r] * inv);
        *(f16x4*)(ao + (size_t)(b * 2048 + q0 + lr) * 512 + h * 64 + dg * 16 + lg * 4) = ov;
    }
}

extern "C" void kernel_launch(void* const* d_in, const int* in_sizes, int n_in,
                              void* d_out, int out_size, void* d_ws, size_t ws_size,
                              hipStream_t stream) {
    const float* x   = (const float*)d_in[0];
    const float* Wq  = (const float*)d_in[1];
    const float* Wkv = (const float*)d_in[2];
    const float* Wo  = (const float*)d_in[3];
    const float* bo  = (const float*)d_in[4];
    float* out = (float*)d_out;

    f16* xb    = (f16*)d_ws;                  // [4096][1024]
    f16* wqkvT = xb + 4096 * 1024;            // [1536][1024]
    f16* woT   = wqkvT + 1536 * 1024;         // [1024][512]
    f16* qkb   = woT + 1024 * 512;            // [4096][QKB_LD]  (Q*CEXP | K)
    f16* vtb   = qkb + 4096 * QKB_LD;         // [16][64][VTB_LD] V^T (padded)
    f16* ao    = vtb + 16 * 64 * VTB_LD;      // [4096][512]

    conv_f32_f16_k<<<2048, 256, 0, stream>>>(x, xb);
    transpose_conv_k<<<dim3(16, 32), 256, 0, stream>>>(Wq, wqkvT, 512, 1024, 0);
    transpose_conv_k<<<dim3(32, 32), 256, 0, stream>>>(Wkv, wqkvT, 1024, 1024, 512);
    transpose_conv_k<<<dim3(32, 16), 256, 0, stream>>>(Wo, woT, 1024, 512, 0);

    gemm_k<0, 64><<<32 * 24, 256, 0, stream>>>(xb, wqkvT, qkb, vtb, nullptr, nullptr, 1024, 24);
    attn_k<<<512, 256, 0, stream>>>(qkb, vtb, ao);
    gemm_k<1, 128><<<32 * 8, 256, 0, stream>>>(ao, woT, nullptr, nullptr, out, bo, 512, 8);
}

// Round 7
// 93.511 us; speedup vs baseline: 1.1677x; 1.1287x over previous
//
#include <hip/hip_runtime.h>

typedef _Float16 f16;
typedef __attribute__((ext_vector_type(4))) _Float16 f16x4;
typedef __attribute__((ext_vector_type(8))) _Float16 f16x8;
typedef __attribute__((ext_vector_type(4))) float f32x4;

#define CEXP 0.18033688011112042f  /* 0.125 * log2(e) : folded into Q at GEMM epilogue */
#define QKB_LD 1056   /* 1024 + 32: L2 channel spread */

__device__ __forceinline__ void gload16(const f16* g, f16* l) {
    __builtin_amdgcn_global_load_lds((const __attribute__((address_space(1))) void*)g,
                                     (__attribute__((address_space(3))) void*)l, 16, 0, 0);
}

// ---------------- fp32 -> f16 convert (vectorized) ----------------
__global__ __launch_bounds__(256) void conv_f32_f16_k(const float* __restrict__ in,
                                                      f16* __restrict__ out) {
    int idx = (blockIdx.x * 256 + threadIdx.x) * 8;
    float4 a = *(const float4*)(in + idx);
    float4 b = *(const float4*)(in + idx + 4);
    f16x8 o;
    o[0] = (f16)a.x; o[1] = (f16)a.y; o[2] = (f16)a.z; o[3] = (f16)a.w;
    o[4] = (f16)b.x; o[5] = (f16)b.y; o[6] = (f16)b.z; o[7] = (f16)b.w;
    *(f16x8*)(out + idx) = o;
}

// ---- transpose + convert: out[(row_off+n)*ldo + k] = in[k*N + n] ----
__global__ __launch_bounds__(256) void transpose_conv_k(const float* __restrict__ in,
                                                        f16* __restrict__ out,
                                                        int N, int ldo, int row_off) {
    __shared__ float tile[32][33];
    int tx = threadIdx.x & 31, ty = threadIdx.x >> 5;  // 32 x 8
    int n0 = blockIdx.x * 32, k0 = blockIdx.y * 32;
#pragma unroll
    for (int j = 0; j < 4; j++)
        tile[ty + j * 8][tx] = in[(size_t)(k0 + ty + j * 8) * N + n0 + tx];
    __syncthreads();
#pragma unroll
    for (int j = 0; j < 4; j++)
        out[(size_t)(row_off + n0 + ty + j * 8) * ldo + k0 + tx] = (f16)tile[tx][ty + j * 8];
}

// ---------------- 128xBN f16 MFMA GEMM (m97 structure) ----------------
// MODE 0: f16 to Cqk (Q cols pre-scaled by CEXP); V written FRAGMENT-MAJOR to Cvt:
//   vtb2[pair][t][kg][dgp][lane=lga*16+lra][dh*4+e] so attn stages it linearly and
//   PV reads are conflict-free ds_read_b128. (e==r, lga==lg, kg==(w*2+i)&3 per thread.)
// MODE 1: fp32 + bias to Cout.
template <int MODE, int BN>
__global__ __launch_bounds__(256) void gemm_k(
    const f16* __restrict__ A, const f16* __restrict__ Bt,
    f16* __restrict__ Cqk, f16* __restrict__ Cvt,
    float* __restrict__ Cout, const float* __restrict__ bias,
    int K, int NTILES) {
    __shared__ __align__(16) f16 As[128 * 64];
    __shared__ __align__(16) f16 Bs[BN * 64];
    constexpr int MI = (BN == 128) ? 4 : 2;
    int bid = blockIdx.x;
    int nt = bid % NTILES, mt = bid / NTILES;
    int m0 = mt * 128, n0 = nt * BN;
    int tid = threadIdx.x;
    int lane = tid & 63, w = tid >> 6;
    int rowBase = (BN == 128) ? (w >> 1) * 64 : w * 32;
    int colBase = (BN == 128) ? (w & 1) * 64 : 0;
    int lr = lane & 15, lg = lane >> 4;
    int rowL = lane >> 3;
    int colL = (lane & 7) * 8;
    int bRow0 = (BN == 128) ? w * 32 : w * 16;
    const f16* aSrc = A + (size_t)(m0 + w * 32 + rowL) * K + colL;
    const f16* bSrc = Bt + (size_t)(n0 + bRow0 + rowL) * K + colL;
    f32x4 acc[MI][4] = {};

    for (int k0 = 0; k0 < K; k0 += 64) {
#pragma unroll
        for (int j = 0; j < 4; j++)
            gload16(aSrc + k0 + (size_t)(j * 8) * K, &As[(w * 32 + j * 8) * 64]);
#pragma unroll
        for (int j = 0; j < (BN == 128 ? 4 : 2); j++)
            gload16(bSrc + k0 + (size_t)(j * 8) * K, &Bs[(bRow0 + j * 8) * 64]);
        __syncthreads();
#pragma unroll
        for (int ks = 0; ks < 2; ks++) {
            f16x8 af[MI], bf[4];
#pragma unroll
            for (int i = 0; i < MI; i++)
                af[i] = *(const f16x8*)(&As[(rowBase + i * 16 + lr) * 64 + ks * 32 + lg * 8]);
#pragma unroll
            for (int j = 0; j < 4; j++)
                bf[j] = *(const f16x8*)(&Bs[(colBase + j * 16 + lr) * 64 + ks * 32 + lg * 8]);
#pragma unroll
            for (int i = 0; i < MI; i++)
#pragma unroll
                for (int j = 0; j < 4; j++)
                    acc[i][j] = __builtin_amdgcn_mfma_f32_16x16x32_f16(af[i], bf[j], acc[i][j], 0, 0, 0);
        }
        __syncthreads();
    }

#pragma unroll
    for (int i = 0; i < MI; i++) {
#pragma unroll
        for (int j = 0; j < 4; j++) {
            int row = m0 + rowBase + i * 16 + lg * 4;
            int col = n0 + colBase + j * 16 + lr;
            if (MODE == 1) {
                float bv = bias[col];
#pragma unroll
                for (int r = 0; r < 4; r++)
                    Cout[(size_t)(row + r) * 1024 + col] = acc[i][j][r] + bv;
            } else {
                if (col < 1024) {
                    float sc = (col < 512) ? CEXP : 1.0f;
#pragma unroll
                    for (int r = 0; r < 4; r++)
                        Cqk[(size_t)(row + r) * QKB_LD + col] = (f16)(acc[i][j][r] * sc);
                } else {
                    // fragment-major V^T write (one f16x4 store, e = r)
                    int c = col - 1024;
                    int hh = c >> 6, d = c & 63;
                    int bb = row >> 11, n = row & 2047;
                    int pr = bb * 8 + hh;
                    int tt = n >> 6, kvl = n & 63;
                    int kg = kvl >> 4, lga = (kvl >> 2) & 3;
                    int dgp = d >> 5, dh = (d >> 4) & 1, lra = d & 15;
                    f16x4 ov;
#pragma unroll
                    for (int r = 0; r < 4; r++) ov[r] = (f16)acc[i][j][r];
                    size_t idx = ((((size_t)(pr * 32 + tt) * 4 + kg) * 2 + dgp) * 64
                                  + lga * 16 + lra) * 8 + dh * 4;
                    *(f16x4*)(Cvt + idx) = ov;
                }
            }
        }
    }
}

// ---------------- flash attention: QK(t+1) || softmax(t), shuffle-free softmax ----------------
// 4 waves x 16 q-rows, KVBLK=64. K: 4 LDS buffers (swizzled); V: 3 buffers,
// fragment-major (conflict-free b128, zero offset math). Counted vmcnt(4), raw
// barriers, no drain. Lane-local defer-max vote (no shuffles common path);
// per-lane l partials reduced once after the loop.
__global__ __launch_bounds__(256, 2) void attn_k(const f16* __restrict__ qkb,
                                                 const f16* __restrict__ vt2,
                                                 f16* __restrict__ ao) {
    __shared__ __align__(16) f16 Ks[4 * 4096];   // 4 x 8 KB
    __shared__ __align__(16) f16 Vs[3 * 4096];   // 3 x 8 KB

    int bid = blockIdx.x;
    int xcd = bid & 7;
    int pair = xcd * 2 + ((bid >> 3) & 1);  // pin each pair's K/V to one XCD L2
    int qblk = bid >> 4;                    // 0..31
    int b = pair >> 3, h = pair & 7;
    int tid = threadIdx.x;
    int lane = tid & 63, w = tid >> 6;
    int lr = lane & 15, lg = lane >> 4;
    int q0 = qblk * 64 + w * 16;

    const f16* qb = qkb + (size_t)b * 2048 * QKB_LD + h * 64;
    const f16* kb = qb + 512;

    f16x8 qf0 = *(const f16x8*)(qb + (size_t)(q0 + lr) * QKB_LD + lg * 8);
    f16x8 qf1 = *(const f16x8*)(qb + (size_t)(q0 + lr) * QKB_LD + 32 + lg * 8);
    asm volatile("s_waitcnt vmcnt(0)" ::: "memory");  // drain Q: loop counting sees only staging

    // K staging: inverse-swizzled source, linear LDS dest
    int srcCol = (((lane & 7) ^ (lane >> 3)) << 3);
    int rowL = lane >> 3;
    const f16* ksrc = kb + (size_t)(w * 16 + rowL) * QKB_LD + srcCol;
    // V staging: fragment-major, fully linear (wave w owns slabs 2w, 2w+1)
    const f16* vsrc = vt2 + ((size_t)(pair * 32) * 8 + 2 * w) * 512 + lane * 8;

    auto stageK = [&](int buf, int kv0) {
        f16* dst = &Ks[buf * 4096 + (w * 16) * 64];
        gload16(ksrc + (size_t)kv0 * QKB_LD, dst);
        gload16(ksrc + (size_t)(kv0 + 8) * QKB_LD, dst + 8 * 64);
    };
    auto stageV = [&](int buf, int tile) {
        const f16* s = vsrc + (size_t)tile * 4096;
        f16* dst = &Vs[buf * 4096 + (2 * w) * 512];
        gload16(s, dst);
        gload16(s + 512, dst + 512);
    };

    stageK(0, 0); stageV(0, 0); stageK(1, 64); stageV(1, 1); stageK(2, 128);
    asm volatile("s_waitcnt vmcnt(4)" ::: "memory");  // K0,V0,K1 landed; V1,K2 in flight
    __builtin_amdgcn_s_barrier();
    asm volatile("" ::: "memory");

    int kOffA = (lg * 8) ^ ((lr & 7) << 3);

    f32x4 acc[4] = {};
    float m = -INFINITY, lp = 0.f;
    f32x4 sA[4], sB[4];

    // QK(0) -> sA
    {
        __builtin_amdgcn_s_setprio(1);
#pragma unroll
        for (int kg = 0; kg < 4; kg++) {
            const f16* krow = &Ks[(kg * 16 + lr) * 64];
            f16x8 ka0 = *(const f16x8*)(krow + kOffA);
            f16x8 ka1 = *(const f16x8*)(krow + (kOffA ^ 32));
            f32x4 z = {};
            z = __builtin_amdgcn_mfma_f32_16x16x32_f16(ka0, qf0, z, 0, 0, 0);
            sA[kg] = __builtin_amdgcn_mfma_f32_16x16x32_f16(ka1, qf1, z, 0, 0, 0);
        }
        __builtin_amdgcn_s_setprio(0);
    }

    auto body = [&](f32x4 (&sCur)[4], f32x4 (&sNxt)[4], int t, int vIdx) {
        // A. stage K[t+3], V[t+2] (guarded)
        if (t <= 28) stageK((t + 3) & 3, (t + 3) * 64);
        if (t <= 29) stageV(vIdx == 0 ? 2 : vIdx - 1, t + 2);

        // B. QK(t+1) from landed K[(t+1)&3] — MFMA pipe fills under softmax VALU
        if (t < 31) {
            const f16* kbuf = &Ks[((t + 1) & 3) * 4096];
            __builtin_amdgcn_s_setprio(1);
#pragma unroll
            for (int kg = 0; kg < 4; kg++) {
                const f16* krow = kbuf + (kg * 16 + lr) * 64;
                f16x8 ka0 = *(const f16x8*)(krow + kOffA);
                f16x8 ka1 = *(const f16x8*)(krow + (kOffA ^ 32));
                f32x4 z = {};
                z = __builtin_amdgcn_mfma_f32_16x16x32_f16(ka0, qf0, z, 0, 0, 0);
                sNxt[kg] = __builtin_amdgcn_mfma_f32_16x16x32_f16(ka1, qf1, z, 0, 0, 0);
            }
            __builtin_amdgcn_s_setprio(0);
        }

        // C. softmax(sCur): lane-local defer-max vote, zero shuffles common path
        float x0 = fmaxf(fmaxf(sCur[0][0], sCur[0][1]), fmaxf(sCur[0][2], sCur[0][3]));
        float x1 = fmaxf(fmaxf(sCur[1][0], sCur[1][1]), fmaxf(sCur[1][2], sCur[1][3]));
        float x2 = fmaxf(fmaxf(sCur[2][0], sCur[2][1]), fmaxf(sCur[2][2], sCur[2][3]));
        float x3 = fmaxf(fmaxf(sCur[3][0], sCur[3][1]), fmaxf(sCur[3][2], sCur[3][3]));
        float ownmx = fmaxf(fmaxf(x0, x1), fmaxf(x2, x3));
        if (!__all(ownmx - m <= 8.f)) {
            float mx = fmaxf(ownmx, __shfl_xor(ownmx, 16, 64));
            mx = fmaxf(mx, __shfl_xor(mx, 32, 64));
            float mn = fmaxf(m, mx);
            float alpha = __builtin_amdgcn_exp2f(m - mn);
            m = mn;
            lp *= alpha;
#pragma unroll
            for (int dg = 0; dg < 4; dg++)
#pragma unroll
                for (int r = 0; r < 4; r++) acc[dg][r] *= alpha;
        }
        f16x4 pf[4];
#pragma unroll
        for (int kg = 0; kg < 4; kg++) {
            float p0 = __builtin_amdgcn_exp2f(sCur[kg][0] - m);
            float p1 = __builtin_amdgcn_exp2f(sCur[kg][1] - m);
            float p2 = __builtin_amdgcn_exp2f(sCur[kg][2] - m);
            float p3 = __builtin_amdgcn_exp2f(sCur[kg][3] - m);
            pf[kg][0] = (f16)p0; pf[kg][1] = (f16)p1;
            pf[kg][2] = (f16)p2; pf[kg][3] = (f16)p3;
            lp += (p0 + p1) + (p2 + p3);
        }

        // D. PV: conflict-free b128, one vaddr + imm offsets
        const f16* vl = &Vs[vIdx * 4096] + lane * 8;
        __builtin_amdgcn_s_setprio(1);
#pragma unroll
        for (int kg = 0; kg < 4; kg++)
#pragma unroll
            for (int dgp = 0; dgp < 2; dgp++) {
                f16x8 vv = *(const f16x8*)(vl + (kg * 2 + dgp) * 512);
                f16x4 vlo = __builtin_shufflevector(vv, vv, 0, 1, 2, 3);
                f16x4 vhi = __builtin_shufflevector(vv, vv, 4, 5, 6, 7);
                acc[dgp * 2]     = __builtin_amdgcn_mfma_f32_16x16x16f16(vlo, pf[kg], acc[dgp * 2], 0, 0, 0);
                acc[dgp * 2 + 1] = __builtin_amdgcn_mfma_f32_16x16x16f16(vhi, pf[kg], acc[dgp * 2 + 1], 0, 0, 0);
            }
        __builtin_amdgcn_s_setprio(0);

        // E. counted wait (K[t+2],V[t+1] landed; newer stay in flight) + raw barrier
        if (t <= 28)      { asm volatile("s_waitcnt vmcnt(4)" ::: "memory"); }
        else if (t == 29) { asm volatile("s_waitcnt vmcnt(2)" ::: "memory"); }
        else if (t == 30) { asm volatile("s_waitcnt vmcnt(0)" ::: "memory"); }
        if (t < 31) {
            __builtin_amdgcn_s_barrier();
            asm volatile("" ::: "memory");
        }
    };

    int vIdx = 0;
    for (int u = 0; u < 16; u++) {
        body(sA, sB, 2 * u, vIdx);     vIdx = (vIdx == 2) ? 0 : vIdx + 1;
        body(sB, sA, 2 * u + 1, vIdx); vIdx = (vIdx == 2) ? 0 : vIdx + 1;
    }

    lp += __shfl_xor(lp, 16, 64);
    lp += __shfl_xor(lp, 32, 64);
    float inv = 1.f / lp;
#pragma unroll
    for (int dg = 0; dg < 4; dg++) {
        f16x4 ov;
#pragma unroll
        for (int r = 0; r < 4; r++) ov[r] = (f16)(acc[dg][r] * inv);
        *(f16x4*)(ao + (size_t)(b * 2048 + q0 + lr) * 512 + h * 64 + dg * 16 + lg * 4) = ov;
    }
}

extern "C" void kernel_launch(void* const* d_in, const int* in_sizes, int n_in,
                              void* d_out, int out_size, void* d_ws, size_t ws_size,
                              hipStream_t stream) {
    const float* x   = (const float*)d_in[0];
    const float* Wq  = (const float*)d_in[1];
    const float* Wkv = (const float*)d_in[2];
    const float* Wo  = (const float*)d_in[3];
    const float* bo  = (const float*)d_in[4];
    float* out = (float*)d_out;

    f16* xb    = (f16*)d_ws;                  // [4096][1024]
    f16* wqkvT = xb + 4096 * 1024;            // [1536][1024]
    f16* woT   = wqkvT + 1536 * 1024;         // [1024][512]
    f16* qkb   = woT + 1024 * 512;            // [4096][QKB_LD]  (Q*CEXP | K)
    f16* vtb2  = qkb + 4096 * QKB_LD;         // [16][32][8][512] fragment-major V^T
    f16* ao    = vtb2 + 16 * 32 * 4096;       // [4096][512]

    conv_f32_f16_k<<<2048, 256, 0, stream>>>(x, xb);
    transpose_conv_k<<<dim3(16, 32), 256, 0, stream>>>(Wq, wqkvT, 512, 1024, 0);
    transpose_conv_k<<<dim3(32, 32), 256, 0, stream>>>(Wkv, wqkvT, 1024, 1024, 512);
    transpose_conv_k<<<dim3(32, 16), 256, 0, stream>>>(Wo, woT, 1024, 512, 0);

    gemm_k<0, 64><<<32 * 24, 256, 0, stream>>>(xb, wqkvT, qkb, vtb2, nullptr, nullptr, 1024, 24);
    attn_k<<<512, 256, 0, stream>>>(qkb, vtb2, ao);
    gemm_k<1, 128><<<32 * 8, 256, 0, stream>>>(ao, woT, nullptr, nullptr, out, bo, 512, 8);
}